// Round 3
// baseline (1050.186 us; speedup 1.0000x reference)
//
#include <hip/hip_runtime.h>
#include <cstdint>

#define NPTS 8192
#define NB 8
#define DS 512
#define CF 64
#define KNN 32

typedef float v2f __attribute__((ext_vector_type(2)));

// ---- DPP wave-64 reductions (VALU only, no DS pipe) ----------------------
__device__ __forceinline__ float wave_max_bcast(float x) {
  int v;
  v = __builtin_amdgcn_update_dpp(0, __float_as_int(x), 0x111, 0xf, 0xf, true); x = fmaxf(x, __int_as_float(v));
  v = __builtin_amdgcn_update_dpp(0, __float_as_int(x), 0x112, 0xf, 0xf, true); x = fmaxf(x, __int_as_float(v));
  v = __builtin_amdgcn_update_dpp(0, __float_as_int(x), 0x114, 0xf, 0xf, true); x = fmaxf(x, __int_as_float(v));
  v = __builtin_amdgcn_update_dpp(0, __float_as_int(x), 0x118, 0xf, 0xf, true); x = fmaxf(x, __int_as_float(v));
  v = __builtin_amdgcn_update_dpp(0, __float_as_int(x), 0x142, 0xf, 0xf, true); x = fmaxf(x, __int_as_float(v));
  v = __builtin_amdgcn_update_dpp(0, __float_as_int(x), 0x143, 0xf, 0xf, true); x = fmaxf(x, __int_as_float(v));
  return __int_as_float(__builtin_amdgcn_readlane(__float_as_int(x), 63));
}

__device__ __forceinline__ float wave_sum_bcast(float x) {
  int v;
  v = __builtin_amdgcn_update_dpp(0, __float_as_int(x), 0x111, 0xf, 0xf, true); x += __int_as_float(v);
  v = __builtin_amdgcn_update_dpp(0, __float_as_int(x), 0x112, 0xf, 0xf, true); x += __int_as_float(v);
  v = __builtin_amdgcn_update_dpp(0, __float_as_int(x), 0x114, 0xf, 0xf, true); x += __int_as_float(v);
  v = __builtin_amdgcn_update_dpp(0, __float_as_int(x), 0x118, 0xf, 0xf, true); x += __int_as_float(v);
  v = __builtin_amdgcn_update_dpp(0, __float_as_int(x), 0x142, 0xf, 0xf, true); x += __int_as_float(v);
  v = __builtin_amdgcn_update_dpp(0, __float_as_int(x), 0x143, 0xf, 0xf, true); x += __int_as_float(v);
  return __int_as_float(__builtin_amdgcn_readlane(__float_as_int(x), 63));
}

__global__ __launch_bounds__(64) void zero_kernel(float* __restrict__ acc) {
  if (threadIdx.x < 16) acc[threadIdx.x] = 0.0f;
}

// blocks 0..15: FPS (view=blk>>3, batch=blk&7). blocks 16..143: global cosine.
// __launch_bounds__(512, 2): 8-wave block = 2 waves/EU min -> VGPR cap 256.
// R2's implicit cap of 48 VGPRs spilled the 64-float point arrays to scratch
// (the 2000 cyc/iter mystery); ~90 VGPRs needed, must stay in registers.
__global__ __launch_bounds__(512, 2) void fps_cos_kernel(
    const float* __restrict__ logits, const float* __restrict__ logits1,
    const float* __restrict__ p0first, const float* __restrict__ p0sec,
    int* __restrict__ idxbuf, float* __restrict__ acc) {
  __shared__ unsigned long long winkey[3];  // triple-buffered packed argmax key
  __shared__ float s_sum;
  const int blk = blockIdx.x;
  const int t = threadIdx.x;
  if (blk < 16) {
    const int view = blk >> 3, b = blk & 7;
    const float* p = (view ? p0sec : p0first) + (size_t)b * NPTS * 3;
    int* idx_out = idxbuf + blk * DS;
    // packed pairs: element (j,h) <-> point e = (j + 8*h)*512 + t
    v2f px2[8], py2[8], pz2[8], dist2[8];
#pragma unroll
    for (int j = 0; j < 8; ++j) {
      int e0 = (j * 512 + t) * 3, e1 = ((j + 8) * 512 + t) * 3;
      px2[j] = (v2f){p[e0 + 0], p[e1 + 0]};
      py2[j] = (v2f){p[e0 + 1], p[e1 + 1]};
      pz2[j] = (v2f){p[e0 + 2], p[e1 + 2]};
      dist2[j] = (v2f){3.4e38f, 3.4e38f};
    }
    if (t == 0) {
      idx_out[0] = 0;
      winkey[0] = 0ull; winkey[1] = 0ull; winkey[2] = 0ull;
    }
    float wx = p[0], wy = p[1], wz = p[2];  // seed = point 0
    __syncthreads();
    for (int it = 0; it < DS - 1; ++it) {
      v2f wx2 = (v2f){wx, wx}, wy2 = (v2f){wy, wy}, wz2 = (v2f){wz, wz};
      v2f lm2 = (v2f){-1.0f, -1.0f};
#pragma unroll
      for (int j = 0; j < 8; ++j) {
        v2f dx = px2[j] - wx2, dy = py2[j] - wy2, dz = pz2[j] - wz2;
        v2f nd = dx * dx + dy * dy + dz * dz;  // v_pk_mul + 2x v_pk_fma
        v2f d = __builtin_elementwise_min(dist2[j], nd);
        dist2[j] = d;
        lm2 = __builtin_elementwise_max(lm2, d);
      }
      float lm = fmaxf(lm2.x, lm2.y);
      float m = wave_max_bcast(lm);  // VALU-only wave max, broadcast
      if (lm == m) {
        // this thread holds a wave max; smallest (j+8h) wins => smallest e
        int jbest = 0;
#pragma unroll
        for (int jp = 15; jp >= 0; --jp) {
          int j = jp & 7, h = jp >> 3;
          float dv = h ? dist2[j].y : dist2[j].x;
          if (dv == lm) jbest = jp;
        }
        unsigned e = (unsigned)(jbest * 512 + t);
        // key: larger dist wins; ties -> smaller element index (jnp.argmax)
        unsigned long long key =
            (((unsigned long long)__float_as_uint(lm)) << 32) | (8191u - e);
        atomicMax(&winkey[it % 3], key);
      }
      if (t == 0) winkey[(it + 1) % 3] = 0ull;  // reset slot 2 barriers away
      __syncthreads();
      unsigned long long k = winkey[it % 3];
      unsigned e = 8191u - (unsigned)(k & 0xffffffffu);
      if (t == 0) idx_out[it + 1] = (int)e;
      // uniform-address reload of winner coords (L2-hit broadcast)
      wx = p[e * 3 + 0]; wy = p[e * 3 + 1]; wz = p[e * 3 + 2];
    }
  } else {
    // global per-point cosine loss: one thread per row of 64
    if (t == 0) s_sum = 0.0f;
    __syncthreads();
    const int row = (blk - 16) * 512 + t;  // 0..65535
    const float4* A = (const float4*)(logits + (size_t)row * CF);
    const float4* Bv = (const float4*)(logits1 + (size_t)row * CF);
    float ab = 0.f, aa = 0.f, bb = 0.f;
#pragma unroll
    for (int i = 0; i < 16; ++i) {
      float4 a = A[i], c = Bv[i];
      ab += a.x * c.x + a.y * c.y + a.z * c.z + a.w * c.w;
      aa += a.x * a.x + a.y * a.y + a.z * a.z + a.w * a.w;
      bb += c.x * c.x + c.y * c.y + c.z * c.z + c.w * c.w;
    }
    float cv = ab / fmaxf(sqrtf(aa) * sqrtf(bb), 1e-8f);
    cv = wave_sum_bcast(cv);
    if ((t & 63) == 0) atomicAdd(&s_sum, cv);
    __syncthreads();
    if (t == 0) atomicAdd(&acc[0], s_sum);
  }
}

// scan per-wave-replicated 256-bin histograms, pick bin containing rrank
__device__ __forceinline__ void radix_scan4(int (*hist)[256], int rrank, int* s_bl, int t) {
  if (t < 64) {
    int h0 = 0, h1 = 0, h2 = 0, h3 = 0;
#pragma unroll
    for (int w = 0; w < 4; ++w) {
      h0 += hist[w][t * 4 + 0]; h1 += hist[w][t * 4 + 1];
      h2 += hist[w][t * 4 + 2]; h3 += hist[w][t * 4 + 3];
    }
    int s = h0 + h1 + h2 + h3;
    int inc = s;
#pragma unroll
    for (int o = 1; o < 64; o <<= 1) {
      int v = __shfl_up(inc, o, 64);
      if (t >= o) inc += v;
    }
    int exc = inc - s;
    bool has = (rrank >= exc) && (rrank < inc);
    unsigned long long mask = __ballot(has);
    int win = __ffsll(mask) - 1;
    int wexc = __shfl(exc, win, 64);
    int wh0 = __shfl(h0, win, 64), wh1 = __shfl(h1, win, 64);
    int wh2 = __shfl(h2, win, 64);
    int r2 = rrank - wexc;
    int bin, less;
    if (r2 < wh0) { bin = 0; less = 0; }
    else if (r2 < wh0 + wh1) { bin = 1; less = wh0; }
    else if (r2 < wh0 + wh1 + wh2) { bin = 2; less = wh0 + wh1; }
    else { bin = 3; less = wh0 + wh1 + wh2; }
    if (t == 0) { s_bl[0] = win * 4 + bin; s_bl[1] = wexc + less; }
  }
  __syncthreads();
}

// one block (256 thr) per query; exact top-32 set via 4-pass radix select
__global__ __launch_bounds__(256) void knn_kernel(
    const float* __restrict__ p0first, const float* __restrict__ p0sec,
    const int* __restrict__ idxbuf, int* __restrict__ knnbuf) {
  __shared__ int hist[4][256];  // per-wave replicated: keys cluster in few bins
  __shared__ int s_bl[2];
  __shared__ int ctr, eqctr;
  __shared__ int eq[256];
  const int g = blockIdx.x;  // 0..8191 : view*4096 + b*512 + m
  const int t = threadIdx.x;
  const int w = t >> 6;
  const int view = g >> 12, b = (g >> 9) & 7;
  const float* p = (view ? p0sec : p0first) + (size_t)b * NPTS * 3;
  const int qi = idxbuf[g];
  const float qx = p[qi * 3], qy = p[qi * 3 + 1], qz = p[qi * 3 + 2];
  const float qq = qx * qx + qy * qy + qz * qz;
  unsigned sk[32];
#pragma unroll
  for (int j = 0; j < 32; ++j) {
    int e = j * 256 + t;
    float sx = p[e * 3], sy = p[e * 3 + 1], sz = p[e * 3 + 2];
    float ss = sx * sx + sy * sy + sz * sz;
    float dt = qx * sx + qy * sy + qz * sz;
    float d = qq + ss - 2.0f * dt;  // same formula as reference
    unsigned u = __float_as_uint(d);
    u = (u & 0x80000000u) ? ~u : (u | 0x80000000u);  // sortable
    sk[j] = u;
  }
  int rrank = 31;  // 0-indexed rank of 32nd smallest
  unsigned prefix = 0;
  // pass 0
#pragma unroll
  for (int k = 0; k < 4; ++k) ((int*)hist)[k * 256 + t] = 0;
  __syncthreads();
#pragma unroll
  for (int j = 0; j < 32; ++j) atomicAdd(&hist[w][sk[j] >> 24], 1);
  __syncthreads();
  radix_scan4(hist, rrank, s_bl, t);
  prefix = (unsigned)s_bl[0];
  rrank -= s_bl[1];
  // passes 1..3
  for (int pass = 1; pass < 4; ++pass) {
    const int shift = 24 - pass * 8;
#pragma unroll
    for (int k = 0; k < 4; ++k) ((int*)hist)[k * 256 + t] = 0;
    __syncthreads();
#pragma unroll
    for (int j = 0; j < 32; ++j) {
      unsigned u = sk[j];
      if ((u >> (shift + 8)) == prefix) atomicAdd(&hist[w][(u >> shift) & 255], 1);
    }
    __syncthreads();
    radix_scan4(hist, rrank, s_bl, t);
    prefix = (prefix << 8) | (unsigned)s_bl[0];
    rrank -= s_bl[1];
  }
  // output: all keys < V, plus (rrank+1) smallest-index keys == V. Order irrelevant.
  if (t == 0) { ctr = 0; eqctr = 0; }
  __syncthreads();
  const unsigned V = prefix;
  int* out = knnbuf + (size_t)g * KNN;
#pragma unroll
  for (int j = 0; j < 32; ++j) {
    unsigned u = sk[j];
    if (u < V) {
      int s = atomicAdd(&ctr, 1);
      out[s] = j * 256 + t;
    } else if (u == V) {
      int s2 = atomicAdd(&eqctr, 1);
      if (s2 < 256) eq[s2] = j * 256 + t;
    }
  }
  __syncthreads();
  if (t == 0) {
    int need = rrank + 1;
    int E = eqctr; if (E > 256) E = 256;
    int base = 32 - need;
    for (int s = 0; s < need; ++s) {
      int mi = 0;
      for (int i = 1; i < E; ++i)
        if (eq[i] < eq[mi]) mi = i;
      out[base + s] = eq[mi];
      eq[mi] = 0x7fffffff;
    }
  }
}

// one wave per group (lane = feature dim); 4 groups per block; DPP reductions
__global__ __launch_bounds__(256) void group_kernel(
    const float* __restrict__ logits, const float* __restrict__ logits1,
    const int* __restrict__ idxbuf, const int* __restrict__ knnbuf,
    float* __restrict__ acc) {
  __shared__ float ws4[4];
  const int w = threadIdx.x >> 6, lane = threadIdx.x & 63;
  const int wid = blockIdx.x * 4 + w;  // 0..8191
  const int view = wid >> 12, b = (wid >> 9) & 7;
  const float* f = (view ? logits1 : logits) + (size_t)b * NPTS * CF;
  const int* nb = knnbuf + (size_t)wid * KNN;
  const int ci = idxbuf[wid];
  float r[33];
  float avg = 0.0f;
#pragma unroll
  for (int j = 0; j < 33; ++j) {
    int e = (j < 32) ? nb[j] : ci;
    float v = f[(size_t)e * CF + lane];
    r[j] = v;
    avg += v;
  }
  avg *= (1.0f / 33.0f);
  float na = wave_sum_bcast(avg * avg);
  const float rsna = sqrtf(na);
  float loss = 0.0f;
#pragma unroll
  for (int j = 0; j < 33; ++j) {
    float d0 = wave_sum_bcast(r[j] * avg);
    float n0 = wave_sum_bcast(r[j] * r[j]);
    float den = fmaxf(sqrtf(n0) * rsna, 1e-8f);
    loss += -200.0f * (d0 / den) - 0.5f * log1pf(40.0f * n0);
  }
  loss *= (1.0f / 33.0f);
  if (lane == 0) ws4[w] = loss;
  __syncthreads();
  if (threadIdx.x == 0) atomicAdd(&acc[1 + b], ws4[0] + ws4[1] + ws4[2] + ws4[3]);
}

__global__ __launch_bounds__(64) void finalize_kernel(const float* __restrict__ acc,
                                                      float* __restrict__ out) {
  if (threadIdx.x == 0 && blockIdx.x == 0) {
    float gl = -acc[0] / 65536.0f;
    float g = 0.0f;
    for (int b = 0; b < 8; ++b) g = (g + acc[1 + b]) * (1.0f / 512.0f);
    g *= 0.125f;  // / b
    out[0] = gl + g + g;
  }
}

extern "C" void kernel_launch(void* const* d_in, const int* in_sizes, int n_in,
                              void* d_out, int out_size, void* d_ws, size_t ws_size,
                              hipStream_t stream) {
  (void)in_sizes; (void)n_in; (void)out_size; (void)ws_size;
  const float* logits  = (const float*)d_in[0];
  const float* logits1 = (const float*)d_in[1];
  const float* p0first = (const float*)d_in[2];
  const float* p0sec   = (const float*)d_in[3];
  float* out = (float*)d_out;

  float* acc = (float*)d_ws;                 // [0]=cosSum, [1..8]=S[b]
  int* idxbuf = (int*)d_ws + 16;             // [2*8*512]
  int* knnbuf = idxbuf + 2 * NB * DS;        // [2*8*512*32]

  zero_kernel<<<1, 64, 0, stream>>>(acc);
  fps_cos_kernel<<<16 + 128, 512, 0, stream>>>(logits, logits1, p0first, p0sec, idxbuf, acc);
  knn_kernel<<<2 * NB * DS, 256, 0, stream>>>(p0first, p0sec, idxbuf, knnbuf);
  group_kernel<<<2 * NB * DS / 4, 256, 0, stream>>>(logits, logits1, idxbuf, knnbuf, acc);
  finalize_kernel<<<1, 64, 0, stream>>>(acc, out);
}

// Round 4
// 806.600 us; speedup vs baseline: 1.3020x; 1.3020x over previous
//
#include <hip/hip_runtime.h>
#include <cstdint>

#define NPTS 8192
#define NB 8
#define DS 512
#define CF 64
#define KNN 32

typedef float v2f __attribute__((ext_vector_type(2)));

// ---- DPP wave-64 reductions (VALU only, no DS pipe) ----------------------
__device__ __forceinline__ float wave_max_bcast(float x) {
  int v;
  v = __builtin_amdgcn_update_dpp(0, __float_as_int(x), 0x111, 0xf, 0xf, true); x = fmaxf(x, __int_as_float(v));
  v = __builtin_amdgcn_update_dpp(0, __float_as_int(x), 0x112, 0xf, 0xf, true); x = fmaxf(x, __int_as_float(v));
  v = __builtin_amdgcn_update_dpp(0, __float_as_int(x), 0x114, 0xf, 0xf, true); x = fmaxf(x, __int_as_float(v));
  v = __builtin_amdgcn_update_dpp(0, __float_as_int(x), 0x118, 0xf, 0xf, true); x = fmaxf(x, __int_as_float(v));
  v = __builtin_amdgcn_update_dpp(0, __float_as_int(x), 0x142, 0xf, 0xf, true); x = fmaxf(x, __int_as_float(v));
  v = __builtin_amdgcn_update_dpp(0, __float_as_int(x), 0x143, 0xf, 0xf, true); x = fmaxf(x, __int_as_float(v));
  return __int_as_float(__builtin_amdgcn_readlane(__float_as_int(x), 63));
}

__device__ __forceinline__ float wave_sum_bcast(float x) {
  int v;
  v = __builtin_amdgcn_update_dpp(0, __float_as_int(x), 0x111, 0xf, 0xf, true); x += __int_as_float(v);
  v = __builtin_amdgcn_update_dpp(0, __float_as_int(x), 0x112, 0xf, 0xf, true); x += __int_as_float(v);
  v = __builtin_amdgcn_update_dpp(0, __float_as_int(x), 0x114, 0xf, 0xf, true); x += __int_as_float(v);
  v = __builtin_amdgcn_update_dpp(0, __float_as_int(x), 0x118, 0xf, 0xf, true); x += __int_as_float(v);
  v = __builtin_amdgcn_update_dpp(0, __float_as_int(x), 0x142, 0xf, 0xf, true); x += __int_as_float(v);
  v = __builtin_amdgcn_update_dpp(0, __float_as_int(x), 0x143, 0xf, 0xf, true); x += __int_as_float(v);
  return __int_as_float(__builtin_amdgcn_readlane(__float_as_int(x), 63));
}

__global__ __launch_bounds__(64) void zero_kernel(float* __restrict__ acc) {
  if (threadIdx.x < 16) acc[threadIdx.x] = 0.0f;
}

// blocks 0..15: FPS (view=blk>>3, batch=blk&7). blocks 16..143: global cosine.
// Pinned point registers (asm "+v") — R2/R3 showed the allocator rematerializes
// the loop-invariant point loads from L1/L2 every iteration (VGPR_Count stuck
// at 48); the pin makes the values opaque so they must stay resident.
__global__ __launch_bounds__(512, 2) void fps_cos_kernel(
    const float* __restrict__ logits, const float* __restrict__ logits1,
    const float* __restrict__ p0first, const float* __restrict__ p0sec,
    int* __restrict__ idxbuf, float* __restrict__ acc) {
  __shared__ float ldsP[NPTS * 3];          // 96 KB winner-lookup table
  __shared__ unsigned long long winkey[3];  // triple-buffered packed argmax key
  __shared__ float s_sum;
  const int blk = blockIdx.x;
  const int t = threadIdx.x;
  if (blk < 16) {
    const int view = blk >> 3, b = blk & 7;
    const float* p = (view ? p0sec : p0first) + (size_t)b * NPTS * 3;
    int* idx_out = idxbuf + blk * DS;
    // packed pairs: element (j,h) <-> point e = (j + 8*h)*512 + t
    v2f px2[8], py2[8], pz2[8], dist2[8];
#pragma unroll
    for (int j = 0; j < 8; ++j) {
      int e0 = j * 512 + t, e1 = (j + 8) * 512 + t;
      px2[j] = (v2f){p[e0 * 3 + 0], p[e1 * 3 + 0]};
      py2[j] = (v2f){p[e0 * 3 + 1], p[e1 * 3 + 1]};
      pz2[j] = (v2f){p[e0 * 3 + 2], p[e1 * 3 + 2]};
      dist2[j] = (v2f){3.4e38f, 3.4e38f};
      ldsP[e0 * 3 + 0] = px2[j].x; ldsP[e1 * 3 + 0] = px2[j].y;
      ldsP[e0 * 3 + 1] = py2[j].x; ldsP[e1 * 3 + 1] = py2[j].y;
      ldsP[e0 * 3 + 2] = pz2[j].x; ldsP[e1 * 3 + 2] = pz2[j].y;
    }
    // pin: forbid rematerialization of the point loads
#pragma unroll
    for (int j = 0; j < 8; ++j) {
      asm("" : "+v"(px2[j]), "+v"(py2[j]), "+v"(pz2[j]));
    }
    if (t == 0) {
      idx_out[0] = 0;
      winkey[0] = 0ull; winkey[1] = 0ull; winkey[2] = 0ull;
    }
    float wx = p[0], wy = p[1], wz = p[2];  // seed = point 0
    __syncthreads();
    for (int it = 0; it < DS - 1; ++it) {
      v2f wx2 = (v2f){wx, wx}, wy2 = (v2f){wy, wy}, wz2 = (v2f){wz, wz};
      v2f lm2 = (v2f){-1.0f, -1.0f};
#pragma unroll
      for (int j = 0; j < 8; ++j) {
        v2f dx = px2[j] - wx2, dy = py2[j] - wy2, dz = pz2[j] - wz2;
        v2f nd = dx * dx + dy * dy + dz * dz;  // v_pk_mul + 2x v_pk_fma
        v2f d = __builtin_elementwise_min(dist2[j], nd);
        dist2[j] = d;
        lm2 = __builtin_elementwise_max(lm2, d);
      }
      float lm = fmaxf(lm2.x, lm2.y);
      float m = wave_max_bcast(lm);  // VALU-only wave max, broadcast
      if (lm == m) {
        // this thread holds a wave max; smallest (j+8h) wins => smallest e
        int jbest = 0;
#pragma unroll
        for (int jp = 15; jp >= 0; --jp) {
          int j = jp & 7, h = jp >> 3;
          float dv = h ? dist2[j].y : dist2[j].x;
          if (dv == lm) jbest = jp;
        }
        unsigned e = (unsigned)(jbest * 512 + t);
        // key: larger dist wins; ties -> smaller element index (jnp.argmax)
        unsigned long long key =
            (((unsigned long long)__float_as_uint(lm)) << 32) | (8191u - e);
        atomicMax(&winkey[it % 3], key);
      }
      if (t == 0) winkey[(it + 1) % 3] = 0ull;  // reset slot 2 barriers away
      __syncthreads();
      unsigned long long k = winkey[it % 3];
      unsigned e = 8191u - (unsigned)(k & 0xffffffffu);
      if (t == 0) idx_out[it + 1] = (int)e;
      // same-address LDS broadcast of winner coords (no L2 round-trip)
      wx = ldsP[e * 3 + 0]; wy = ldsP[e * 3 + 1]; wz = ldsP[e * 3 + 2];
    }
  } else {
    // global per-point cosine loss: one thread per row of 64
    if (t == 0) s_sum = 0.0f;
    __syncthreads();
    const int row = (blk - 16) * 512 + t;  // 0..65535
    const float4* A = (const float4*)(logits + (size_t)row * CF);
    const float4* Bv = (const float4*)(logits1 + (size_t)row * CF);
    float ab = 0.f, aa = 0.f, bb = 0.f;
#pragma unroll
    for (int i = 0; i < 16; ++i) {
      float4 a = A[i], c = Bv[i];
      ab += a.x * c.x + a.y * c.y + a.z * c.z + a.w * c.w;
      aa += a.x * a.x + a.y * a.y + a.z * a.z + a.w * a.w;
      bb += c.x * c.x + c.y * c.y + c.z * c.z + c.w * c.w;
    }
    float cv = ab / fmaxf(sqrtf(aa) * sqrtf(bb), 1e-8f);
    cv = wave_sum_bcast(cv);
    if ((t & 63) == 0) atomicAdd(&s_sum, cv);
    __syncthreads();
    if (t == 0) atomicAdd(&acc[0], s_sum);
  }
}

// scan lane-group-replicated 256-bin histograms, pick bin containing rrank
__device__ __forceinline__ void radix_scan8(int (*hist)[264], int rrank, int* s_bl, int t) {
  if (t < 64) {
    int h0 = 0, h1 = 0, h2 = 0, h3 = 0;
#pragma unroll
    for (int c = 0; c < 8; ++c) {
      h0 += hist[c][t * 4 + 0]; h1 += hist[c][t * 4 + 1];
      h2 += hist[c][t * 4 + 2]; h3 += hist[c][t * 4 + 3];
    }
    int s = h0 + h1 + h2 + h3;
    int inc = s;
#pragma unroll
    for (int o = 1; o < 64; o <<= 1) {
      int v = __shfl_up(inc, o, 64);
      if (t >= o) inc += v;
    }
    int exc = inc - s;
    bool has = (rrank >= exc) && (rrank < inc);
    unsigned long long mask = __ballot(has);
    int win = __ffsll(mask) - 1;
    int wexc = __shfl(exc, win, 64);
    int wh0 = __shfl(h0, win, 64), wh1 = __shfl(h1, win, 64);
    int wh2 = __shfl(h2, win, 64);
    int r2 = rrank - wexc;
    int bin, less;
    if (r2 < wh0) { bin = 0; less = 0; }
    else if (r2 < wh0 + wh1) { bin = 1; less = wh0; }
    else if (r2 < wh0 + wh1 + wh2) { bin = 2; less = wh0 + wh1; }
    else { bin = 3; less = wh0 + wh1 + wh2; }
    if (t == 0) { s_bl[0] = win * 4 + bin; s_bl[1] = wexc + less; }
  }
  __syncthreads();
}

// one block (256 thr) per query; exact top-32 set via 4-pass radix select.
// Histogram replicated by lane-group (lane&7) with 264-padding: LDS atomic
// same-address serialization is INTRA-wave, so split lanes not waves.
__global__ __launch_bounds__(256) void knn_kernel(
    const float* __restrict__ p0first, const float* __restrict__ p0sec,
    const int* __restrict__ idxbuf, int* __restrict__ knnbuf) {
  __shared__ int hist[8][264];
  __shared__ int s_bl[2];
  __shared__ int ctr, eqctr;
  __shared__ int eq[256];
  const int g = blockIdx.x;  // 0..8191 : view*4096 + b*512 + m
  const int t = threadIdx.x;
  const int c = t & 7;
  const int view = g >> 12, b = (g >> 9) & 7;
  const float* p = (view ? p0sec : p0first) + (size_t)b * NPTS * 3;
  const int qi = idxbuf[g];
  const float qx = p[qi * 3], qy = p[qi * 3 + 1], qz = p[qi * 3 + 2];
  const float qq = qx * qx + qy * qy + qz * qz;
  unsigned sk[32];
#pragma unroll
  for (int j = 0; j < 32; ++j) {
    int e = j * 256 + t;
    float sx = p[e * 3], sy = p[e * 3 + 1], sz = p[e * 3 + 2];
    float ss = sx * sx + sy * sy + sz * sz;
    float dt = qx * sx + qy * sy + qz * sz;
    float d = qq + ss - 2.0f * dt;  // same formula as reference
    unsigned u = __float_as_uint(d);
    u = (u & 0x80000000u) ? ~u : (u | 0x80000000u);  // sortable
    sk[j] = u;
  }
  int rrank = 31;  // 0-indexed rank of 32nd smallest
  unsigned prefix = 0;
  // pass 0
  for (int k = t; k < 8 * 264; k += 256) ((int*)hist)[k] = 0;
  __syncthreads();
#pragma unroll
  for (int j = 0; j < 32; ++j) atomicAdd(&hist[c][sk[j] >> 24], 1);
  __syncthreads();
  radix_scan8(hist, rrank, s_bl, t);
  prefix = (unsigned)s_bl[0];
  rrank -= s_bl[1];
  // passes 1..3
  for (int pass = 1; pass < 4; ++pass) {
    const int shift = 24 - pass * 8;
    for (int k = t; k < 8 * 264; k += 256) ((int*)hist)[k] = 0;
    __syncthreads();
#pragma unroll
    for (int j = 0; j < 32; ++j) {
      unsigned u = sk[j];
      if ((u >> (shift + 8)) == prefix) atomicAdd(&hist[c][(u >> shift) & 255], 1);
    }
    __syncthreads();
    radix_scan8(hist, rrank, s_bl, t);
    prefix = (prefix << 8) | (unsigned)s_bl[0];
    rrank -= s_bl[1];
  }
  // output: all keys < V, plus (rrank+1) smallest-index keys == V. Order irrelevant.
  if (t == 0) { ctr = 0; eqctr = 0; }
  __syncthreads();
  const unsigned V = prefix;
  int* out = knnbuf + (size_t)g * KNN;
#pragma unroll
  for (int j = 0; j < 32; ++j) {
    unsigned u = sk[j];
    if (u < V) {
      int s = atomicAdd(&ctr, 1);
      out[s] = j * 256 + t;
    } else if (u == V) {
      int s2 = atomicAdd(&eqctr, 1);
      if (s2 < 256) eq[s2] = j * 256 + t;
    }
  }
  __syncthreads();
  if (t == 0) {
    int need = rrank + 1;
    int E = eqctr; if (E > 256) E = 256;
    int base = 32 - need;
    for (int s = 0; s < need; ++s) {
      int mi = 0;
      for (int i = 1; i < E; ++i)
        if (eq[i] < eq[mi]) mi = i;
      out[base + s] = eq[mi];
      eq[mi] = 0x7fffffff;
    }
  }
}

// one wave per group (lane = feature dim); 4 groups per block; DPP reductions
__global__ __launch_bounds__(256) void group_kernel(
    const float* __restrict__ logits, const float* __restrict__ logits1,
    const int* __restrict__ idxbuf, const int* __restrict__ knnbuf,
    float* __restrict__ acc) {
  __shared__ float ws4[4];
  const int w = threadIdx.x >> 6, lane = threadIdx.x & 63;
  const int wid = blockIdx.x * 4 + w;  // 0..8191
  const int view = wid >> 12, b = (wid >> 9) & 7;
  const float* f = (view ? logits1 : logits) + (size_t)b * NPTS * CF;
  const int* nb = knnbuf + (size_t)wid * KNN;
  const int ci = idxbuf[wid];
  float r[33];
  float avg = 0.0f;
#pragma unroll
  for (int j = 0; j < 33; ++j) {
    int e = (j < 32) ? nb[j] : ci;
    float v = f[(size_t)e * CF + lane];
    r[j] = v;
    avg += v;
  }
  avg *= (1.0f / 33.0f);
  float na = wave_sum_bcast(avg * avg);
  const float rsna = sqrtf(na);
  float loss = 0.0f;
#pragma unroll
  for (int j = 0; j < 33; ++j) {
    float d0 = wave_sum_bcast(r[j] * avg);
    float n0 = wave_sum_bcast(r[j] * r[j]);
    float den = fmaxf(sqrtf(n0) * rsna, 1e-8f);
    loss += -200.0f * (d0 / den) - 0.5f * log1pf(40.0f * n0);
  }
  loss *= (1.0f / 33.0f);
  if (lane == 0) ws4[w] = loss;
  __syncthreads();
  if (threadIdx.x == 0) atomicAdd(&acc[1 + b], ws4[0] + ws4[1] + ws4[2] + ws4[3]);
}

__global__ __launch_bounds__(64) void finalize_kernel(const float* __restrict__ acc,
                                                      float* __restrict__ out) {
  if (threadIdx.x == 0 && blockIdx.x == 0) {
    float gl = -acc[0] / 65536.0f;
    float g = 0.0f;
    for (int b = 0; b < 8; ++b) g = (g + acc[1 + b]) * (1.0f / 512.0f);
    g *= 0.125f;  // / b
    out[0] = gl + g + g;
  }
}

extern "C" void kernel_launch(void* const* d_in, const int* in_sizes, int n_in,
                              void* d_out, int out_size, void* d_ws, size_t ws_size,
                              hipStream_t stream) {
  (void)in_sizes; (void)n_in; (void)out_size; (void)ws_size;
  const float* logits  = (const float*)d_in[0];
  const float* logits1 = (const float*)d_in[1];
  const float* p0first = (const float*)d_in[2];
  const float* p0sec   = (const float*)d_in[3];
  float* out = (float*)d_out;

  float* acc = (float*)d_ws;                 // [0]=cosSum, [1..8]=S[b]
  int* idxbuf = (int*)d_ws + 16;             // [2*8*512]
  int* knnbuf = idxbuf + 2 * NB * DS;        // [2*8*512*32]

  zero_kernel<<<1, 64, 0, stream>>>(acc);
  fps_cos_kernel<<<16 + 128, 512, 0, stream>>>(logits, logits1, p0first, p0sec, idxbuf, acc);
  knn_kernel<<<2 * NB * DS, 256, 0, stream>>>(p0first, p0sec, idxbuf, knnbuf);
  group_kernel<<<2 * NB * DS / 4, 256, 0, stream>>>(logits, logits1, idxbuf, knnbuf, acc);
  finalize_kernel<<<1, 64, 0, stream>>>(acc, out);
}

// Round 5
// 778.456 us; speedup vs baseline: 1.3491x; 1.0362x over previous
//
#include <hip/hip_runtime.h>
#include <cstdint>

#define NPTS 8192
#define NB 8
#define DS 512
#define CF 64
#define KNN 32

typedef float v2f __attribute__((ext_vector_type(2)));

// ---- DPP wave-64 reductions (VALU only, no DS pipe) ----------------------
// row_shr 1/2/4/8 + row_bcast15/31: full wave-64 max accumulates in lane 63.
__device__ __forceinline__ float wave_max63(float x) {
  int v;
  v = __builtin_amdgcn_update_dpp(0, __float_as_int(x), 0x111, 0xf, 0xf, true); x = fmaxf(x, __int_as_float(v));
  v = __builtin_amdgcn_update_dpp(0, __float_as_int(x), 0x112, 0xf, 0xf, true); x = fmaxf(x, __int_as_float(v));
  v = __builtin_amdgcn_update_dpp(0, __float_as_int(x), 0x114, 0xf, 0xf, true); x = fmaxf(x, __int_as_float(v));
  v = __builtin_amdgcn_update_dpp(0, __float_as_int(x), 0x118, 0xf, 0xf, true); x = fmaxf(x, __int_as_float(v));
  v = __builtin_amdgcn_update_dpp(0, __float_as_int(x), 0x142, 0xf, 0xf, true); x = fmaxf(x, __int_as_float(v));
  v = __builtin_amdgcn_update_dpp(0, __float_as_int(x), 0x143, 0xf, 0xf, true); x = fmaxf(x, __int_as_float(v));
  return x;  // valid in lane 63
}

__device__ __forceinline__ float wave_sum_bcast(float x) {
  int v;
  v = __builtin_amdgcn_update_dpp(0, __float_as_int(x), 0x111, 0xf, 0xf, true); x += __int_as_float(v);
  v = __builtin_amdgcn_update_dpp(0, __float_as_int(x), 0x112, 0xf, 0xf, true); x += __int_as_float(v);
  v = __builtin_amdgcn_update_dpp(0, __float_as_int(x), 0x114, 0xf, 0xf, true); x += __int_as_float(v);
  v = __builtin_amdgcn_update_dpp(0, __float_as_int(x), 0x118, 0xf, 0xf, true); x += __int_as_float(v);
  v = __builtin_amdgcn_update_dpp(0, __float_as_int(x), 0x142, 0xf, 0xf, true); x += __int_as_float(v);
  v = __builtin_amdgcn_update_dpp(0, __float_as_int(x), 0x143, 0xf, 0xf, true); x += __int_as_float(v);
  return __int_as_float(__builtin_amdgcn_readlane(__float_as_int(x), 63));
}

__global__ __launch_bounds__(64) void zero_kernel(float* __restrict__ acc) {
  if (threadIdx.x < 16) acc[threadIdx.x] = 0.0f;
}

// blocks 0..15: FPS (view=blk>>3, batch=blk&7). blocks 16..143: global cosine.
// R4 post-mortem: 8 same-address u64 LDS atomicMax per iter (one per wave)
// serialize ~500-800 cyc. Two-phase scheme: plain ds_write of wave maxes ->
// barrier -> gmax from 8 floats -> only the matching wave (~1/8) runs the
// tie-search + single atomicMax.
__global__ __launch_bounds__(512, 2) void fps_cos_kernel(
    const float* __restrict__ logits, const float* __restrict__ logits1,
    const float* __restrict__ p0first, const float* __restrict__ p0sec,
    int* __restrict__ idxbuf, float* __restrict__ acc) {
  __shared__ float ldsP[NPTS * 3];          // 96 KB winner-lookup table
  __shared__ __align__(16) float wmax[8];   // per-wave maxes
  __shared__ unsigned long long winkey[2];  // double-buffered packed argmax key
  __shared__ float s_sum;
  const int blk = blockIdx.x;
  const int t = threadIdx.x;
  if (blk < 16) {
    const int view = blk >> 3, b = blk & 7;
    const float* p = (view ? p0sec : p0first) + (size_t)b * NPTS * 3;
    int* idx_out = idxbuf + blk * DS;
    // packed pairs: element (j,h) <-> point e = (j + 8*h)*512 + t
    v2f px2[8], py2[8], pz2[8], dist2[8];
#pragma unroll
    for (int j = 0; j < 8; ++j) {
      int e0 = j * 512 + t, e1 = (j + 8) * 512 + t;
      px2[j] = (v2f){p[e0 * 3 + 0], p[e1 * 3 + 0]};
      py2[j] = (v2f){p[e0 * 3 + 1], p[e1 * 3 + 1]};
      pz2[j] = (v2f){p[e0 * 3 + 2], p[e1 * 3 + 2]};
      dist2[j] = (v2f){3.4e38f, 3.4e38f};
      ldsP[e0 * 3 + 0] = px2[j].x; ldsP[e1 * 3 + 0] = px2[j].y;
      ldsP[e0 * 3 + 1] = py2[j].x; ldsP[e1 * 3 + 1] = py2[j].y;
      ldsP[e0 * 3 + 2] = pz2[j].x; ldsP[e1 * 3 + 2] = pz2[j].y;
    }
    // pin: forbid rematerialization of the point loads (R4: VGPR 48->88, -100us)
#pragma unroll
    for (int j = 0; j < 8; ++j) {
      asm("" : "+v"(px2[j]), "+v"(py2[j]), "+v"(pz2[j]));
    }
    if (t == 0) {
      idx_out[0] = 0;
      winkey[0] = 0ull; winkey[1] = 0ull;
    }
    float wx = p[0], wy = p[1], wz = p[2];  // seed = point 0
    const int lane = t & 63, wave = t >> 6;
    __syncthreads();
    for (int it = 0; it < DS - 1; ++it) {
      // A: update min-dists, track per-thread max
      v2f wx2 = (v2f){wx, wx}, wy2 = (v2f){wy, wy}, wz2 = (v2f){wz, wz};
      v2f lm2 = (v2f){-1.0f, -1.0f};
#pragma unroll
      for (int j = 0; j < 8; ++j) {
        v2f dx = px2[j] - wx2, dy = py2[j] - wy2, dz = pz2[j] - wz2;
        v2f nd = dx * dx + dy * dy + dz * dz;
        v2f d = __builtin_elementwise_min(dist2[j], nd);
        dist2[j] = d;
        lm2 = __builtin_elementwise_max(lm2, d);
      }
      float lm = fmaxf(lm2.x, lm2.y);
      // B: wave max -> lane 63 -> LDS (no atomic)
      float wm = wave_max63(lm);
      if (lane == 63) wmax[wave] = wm;
      if (t == 0) winkey[(it + 1) & 1] = 0ull;  // reset other slot
      __syncthreads();
      // C: block max from the 8 wave maxes (broadcast reads)
      float4 m0 = *(const float4*)&wmax[0];
      float4 m1 = *(const float4*)&wmax[4];
      float gmax = fmaxf(fmaxf(fmaxf(m0.x, m0.y), fmaxf(m0.z, m0.w)),
                         fmaxf(fmaxf(m1.x, m1.y), fmaxf(m1.z, m1.w)));
      // D: only threads owning the block max (≈1 wave) resolve the index
      if (lm == gmax) {
        int jbest = 0;
#pragma unroll
        for (int jp = 15; jp >= 0; --jp) {
          int j = jp & 7, h = jp >> 3;
          float dv = h ? dist2[j].y : dist2[j].x;
          if (dv == lm) jbest = jp;
        }
        unsigned e = (unsigned)(jbest * 512 + t);
        // key: larger dist wins; ties -> smaller element index (jnp.argmax)
        unsigned long long key =
            (((unsigned long long)__float_as_uint(lm)) << 32) | (8191u - e);
        atomicMax(&winkey[it & 1], key);
      }
      __syncthreads();
      // E: read winner, fetch its coords from the LDS table
      unsigned long long k = winkey[it & 1];
      unsigned e = 8191u - (unsigned)(k & 0xffffffffu);
      if (t == 0) idx_out[it + 1] = (int)e;
      wx = ldsP[e * 3 + 0]; wy = ldsP[e * 3 + 1]; wz = ldsP[e * 3 + 2];
    }
  } else {
    // global per-point cosine loss: one thread per row of 64
    if (t == 0) s_sum = 0.0f;
    __syncthreads();
    const int row = (blk - 16) * 512 + t;  // 0..65535
    const float4* A = (const float4*)(logits + (size_t)row * CF);
    const float4* Bv = (const float4*)(logits1 + (size_t)row * CF);
    float ab = 0.f, aa = 0.f, bb = 0.f;
#pragma unroll
    for (int i = 0; i < 16; ++i) {
      float4 a = A[i], c = Bv[i];
      ab += a.x * c.x + a.y * c.y + a.z * c.z + a.w * c.w;
      aa += a.x * a.x + a.y * a.y + a.z * a.z + a.w * a.w;
      bb += c.x * c.x + c.y * c.y + c.z * c.z + c.w * c.w;
    }
    float cv = ab / fmaxf(sqrtf(aa) * sqrtf(bb), 1e-8f);
    cv = wave_sum_bcast(cv);
    if ((t & 63) == 0) atomicAdd(&s_sum, cv);
    __syncthreads();
    if (t == 0) atomicAdd(&acc[0], s_sum);
  }
}

// scan lane-group-replicated 256-bin histograms, pick bin containing rrank
__device__ __forceinline__ void radix_scan8(int (*hist)[264], int rrank, int* s_bl, int t) {
  if (t < 64) {
    int h0 = 0, h1 = 0, h2 = 0, h3 = 0;
#pragma unroll
    for (int c = 0; c < 8; ++c) {
      h0 += hist[c][t * 4 + 0]; h1 += hist[c][t * 4 + 1];
      h2 += hist[c][t * 4 + 2]; h3 += hist[c][t * 4 + 3];
    }
    int s = h0 + h1 + h2 + h3;
    int inc = s;
#pragma unroll
    for (int o = 1; o < 64; o <<= 1) {
      int v = __shfl_up(inc, o, 64);
      if (t >= o) inc += v;
    }
    int exc = inc - s;
    bool has = (rrank >= exc) && (rrank < inc);
    unsigned long long mask = __ballot(has);
    int win = __ffsll(mask) - 1;
    int wexc = __shfl(exc, win, 64);
    int wh0 = __shfl(h0, win, 64), wh1 = __shfl(h1, win, 64);
    int wh2 = __shfl(h2, win, 64);
    int r2 = rrank - wexc;
    int bin, less;
    if (r2 < wh0) { bin = 0; less = 0; }
    else if (r2 < wh0 + wh1) { bin = 1; less = wh0; }
    else if (r2 < wh0 + wh1 + wh2) { bin = 2; less = wh0 + wh1; }
    else { bin = 3; less = wh0 + wh1 + wh2; }
    if (t == 0) { s_bl[0] = win * 4 + bin; s_bl[1] = wexc + less; }
  }
  __syncthreads();
}

// one block (256 thr) per query; exact top-32 set via 4-pass radix select.
__global__ __launch_bounds__(256) void knn_kernel(
    const float* __restrict__ p0first, const float* __restrict__ p0sec,
    const int* __restrict__ idxbuf, int* __restrict__ knnbuf) {
  __shared__ int hist[8][264];
  __shared__ int s_bl[2];
  __shared__ int ctr, eqctr;
  __shared__ int eq[256];
  const int g = blockIdx.x;  // 0..8191 : view*4096 + b*512 + m
  const int t = threadIdx.x;
  const int c = t & 7;
  const int view = g >> 12, b = (g >> 9) & 7;
  const float* p = (view ? p0sec : p0first) + (size_t)b * NPTS * 3;
  const int qi = idxbuf[g];
  const float qx = p[qi * 3], qy = p[qi * 3 + 1], qz = p[qi * 3 + 2];
  const float qq = qx * qx + qy * qy + qz * qz;
  unsigned sk[32];
#pragma unroll
  for (int j = 0; j < 32; ++j) {
    int e = j * 256 + t;
    float sx = p[e * 3], sy = p[e * 3 + 1], sz = p[e * 3 + 2];
    float ss = sx * sx + sy * sy + sz * sz;
    float dt = qx * sx + qy * sy + qz * sz;
    float d = qq + ss - 2.0f * dt;  // same formula as reference
    unsigned u = __float_as_uint(d);
    u = (u & 0x80000000u) ? ~u : (u | 0x80000000u);  // sortable
    sk[j] = u;
  }
  int rrank = 31;  // 0-indexed rank of 32nd smallest
  unsigned prefix = 0;
  // pass 0
  for (int k = t; k < 8 * 264; k += 256) ((int*)hist)[k] = 0;
  __syncthreads();
#pragma unroll
  for (int j = 0; j < 32; ++j) atomicAdd(&hist[c][sk[j] >> 24], 1);
  __syncthreads();
  radix_scan8(hist, rrank, s_bl, t);
  prefix = (unsigned)s_bl[0];
  rrank -= s_bl[1];
  // passes 1..3
  for (int pass = 1; pass < 4; ++pass) {
    const int shift = 24 - pass * 8;
    for (int k = t; k < 8 * 264; k += 256) ((int*)hist)[k] = 0;
    __syncthreads();
#pragma unroll
    for (int j = 0; j < 32; ++j) {
      unsigned u = sk[j];
      if ((u >> (shift + 8)) == prefix) atomicAdd(&hist[c][(u >> shift) & 255], 1);
    }
    __syncthreads();
    radix_scan8(hist, rrank, s_bl, t);
    prefix = (prefix << 8) | (unsigned)s_bl[0];
    rrank -= s_bl[1];
  }
  // output: all keys < V, plus (rrank+1) smallest-index keys == V. Order irrelevant.
  if (t == 0) { ctr = 0; eqctr = 0; }
  __syncthreads();
  const unsigned V = prefix;
  int* out = knnbuf + (size_t)g * KNN;
#pragma unroll
  for (int j = 0; j < 32; ++j) {
    unsigned u = sk[j];
    if (u < V) {
      int s = atomicAdd(&ctr, 1);
      out[s] = j * 256 + t;
    } else if (u == V) {
      int s2 = atomicAdd(&eqctr, 1);
      if (s2 < 256) eq[s2] = j * 256 + t;
    }
  }
  __syncthreads();
  if (t == 0) {
    int need = rrank + 1;
    int E = eqctr; if (E > 256) E = 256;
    int base = 32 - need;
    for (int s = 0; s < need; ++s) {
      int mi = 0;
      for (int i = 1; i < E; ++i)
        if (eq[i] < eq[mi]) mi = i;
      out[base + s] = eq[mi];
      eq[mi] = 0x7fffffff;
    }
  }
}

// one wave per group (lane = feature dim); 4 groups per block; DPP reductions
__global__ __launch_bounds__(256) void group_kernel(
    const float* __restrict__ logits, const float* __restrict__ logits1,
    const int* __restrict__ idxbuf, const int* __restrict__ knnbuf,
    float* __restrict__ acc) {
  __shared__ float ws4[4];
  const int w = threadIdx.x >> 6, lane = threadIdx.x & 63;
  const int wid = blockIdx.x * 4 + w;  // 0..8191
  const int view = wid >> 12, b = (wid >> 9) & 7;
  const float* f = (view ? logits1 : logits) + (size_t)b * NPTS * CF;
  const int* nb = knnbuf + (size_t)wid * KNN;
  const int ci = idxbuf[wid];
  float r[33];
  float avg = 0.0f;
#pragma unroll
  for (int j = 0; j < 33; ++j) {
    int e = (j < 32) ? nb[j] : ci;
    float v = f[(size_t)e * CF + lane];
    r[j] = v;
    avg += v;
  }
  avg *= (1.0f / 33.0f);
  float na = wave_sum_bcast(avg * avg);
  const float rsna = sqrtf(na);
  float loss = 0.0f;
#pragma unroll
  for (int j = 0; j < 33; ++j) {
    float d0 = wave_sum_bcast(r[j] * avg);
    float n0 = wave_sum_bcast(r[j] * r[j]);
    float den = fmaxf(sqrtf(n0) * rsna, 1e-8f);
    loss += -200.0f * (d0 / den) - 0.5f * log1pf(40.0f * n0);
  }
  loss *= (1.0f / 33.0f);
  if (lane == 0) ws4[w] = loss;
  __syncthreads();
  if (threadIdx.x == 0) atomicAdd(&acc[1 + b], ws4[0] + ws4[1] + ws4[2] + ws4[3]);
}

__global__ __launch_bounds__(64) void finalize_kernel(const float* __restrict__ acc,
                                                      float* __restrict__ out) {
  if (threadIdx.x == 0 && blockIdx.x == 0) {
    float gl = -acc[0] / 65536.0f;
    float g = 0.0f;
    for (int b = 0; b < 8; ++b) g = (g + acc[1 + b]) * (1.0f / 512.0f);
    g *= 0.125f;  // / b
    out[0] = gl + g + g;
  }
}

extern "C" void kernel_launch(void* const* d_in, const int* in_sizes, int n_in,
                              void* d_out, int out_size, void* d_ws, size_t ws_size,
                              hipStream_t stream) {
  (void)in_sizes; (void)n_in; (void)out_size; (void)ws_size;
  const float* logits  = (const float*)d_in[0];
  const float* logits1 = (const float*)d_in[1];
  const float* p0first = (const float*)d_in[2];
  const float* p0sec   = (const float*)d_in[3];
  float* out = (float*)d_out;

  float* acc = (float*)d_ws;                 // [0]=cosSum, [1..8]=S[b]
  int* idxbuf = (int*)d_ws + 16;             // [2*8*512]
  int* knnbuf = idxbuf + 2 * NB * DS;        // [2*8*512*32]

  zero_kernel<<<1, 64, 0, stream>>>(acc);
  fps_cos_kernel<<<16 + 128, 512, 0, stream>>>(logits, logits1, p0first, p0sec, idxbuf, acc);
  knn_kernel<<<2 * NB * DS, 256, 0, stream>>>(p0first, p0sec, idxbuf, knnbuf);
  group_kernel<<<2 * NB * DS / 4, 256, 0, stream>>>(logits, logits1, idxbuf, knnbuf, acc);
  finalize_kernel<<<1, 64, 0, stream>>>(acc, out);
}